// Round 2
// baseline (1154.465 us; speedup 1.0000x reference)
//
#include <hip/hip_runtime.h>
#include <math.h>

#define OBS 256
#define ACTD 64
#define NB 8192
#define NT 22
#define NSTEP 15

// ---------------------------------------------------------------------------
// Kernel 1: gi[b,t,j] = bias_ih[j] + sum_k x[b,t,k] * W_ih[j,k]
// R4 structure: ONE thread owns one (b,t) row and computes ALL 96 outputs.
//  - x fetched from HBM exactly once (157 MB total; R3's grid.y splits
//    multiplied x traffic: grid.y=6 -> 1.06 GB FETCH_SIZE, latency-bound).
//  - W_ih addresses are wave-uniform -> compiler emits s_load; weights cost
//    SMEM/lgkm slots, not VALU. VALU is ~pure v_fma_f32 (768 per 8-k block
//    vs 1 x-prefetch), so the kernel is compute-bound: floor ~48 us.
//  - 96 accumulators + 8 xv + prefetch ~ 125 VGPRs; launch_bounds(64,2)
//    gives a 256-reg budget so nothing spills or AGPR-shuffles.
//  - accumulation order (bias, then k ascending) identical to prior rounds
//    -> bit-exact outputs.
// ---------------------------------------------------------------------------
__global__ __launch_bounds__(64, 2) void k1_gi(
    const float* __restrict__ obs, const float* __restrict__ act,
    const float* __restrict__ Wih, const float* __restrict__ bih,
    float* __restrict__ gi)
{
    int g = blockIdx.x * 64 + threadIdx.x;    // row id 0..122879
    int b = g / 15;
    int t = g - b * 15;
    const float* xo = obs + (size_t)(b * NT + t) * OBS;
    const float* xa = act + (size_t)(b * NT + t) * ACTD;

    float acc[96];
#pragma unroll
    for (int j = 0; j < 96; ++j) acc[j] = bih[j];   // uniform -> s_load

    // software-pipelined x: hold current 8 values, prefetch next 8
    float4 a0 = *(const float4*)(xo + 0);
    float4 a1 = *(const float4*)(xo + 4);

#pragma unroll 1
    for (int kb = 0; kb < 312; kb += 8) {
        // prefetch next 8-k block (handles the obs->act seam at k=256)
        const float* nx = (kb + 8 < 256) ? (xo + kb + 8) : (xa + (kb + 8 - 256));
        float4 n0 = *(const float4*)(nx + 0);
        float4 n1 = *(const float4*)(nx + 4);

        float xv[8];
        xv[0]=a0.x; xv[1]=a0.y; xv[2]=a0.z; xv[3]=a0.w;
        xv[4]=a1.x; xv[5]=a1.y; xv[6]=a1.z; xv[7]=a1.w;
#pragma unroll
        for (int j = 0; j < 96; ++j) {
            const float* w = Wih + j * 320 + kb;   // wave-uniform address
#pragma unroll
            for (int kk = 0; kk < 8; ++kk)
                acc[j] = fmaf(w[kk], xv[kk], acc[j]);
        }
        a0 = n0; a1 = n1;
    }
    // epilogue block kb = 312..319 (no prefetch)
    {
        float xv[8];
        xv[0]=a0.x; xv[1]=a0.y; xv[2]=a0.z; xv[3]=a0.w;
        xv[4]=a1.x; xv[5]=a1.y; xv[6]=a1.z; xv[7]=a1.w;
#pragma unroll
        for (int j = 0; j < 96; ++j) {
            const float* w = Wih + j * 320 + 312;
#pragma unroll
            for (int kk = 0; kk < 8; ++kk)
                acc[j] = fmaf(w[kk], xv[kk], acc[j]);
        }
    }

    float4* o = (float4*)(gi + (size_t)g * 96);
#pragma unroll
    for (int j = 0; j < 24; ++j)
        o[j] = make_float4(acc[4*j], acc[4*j+1], acc[4*j+2], acc[4*j+3]);
}

// ---------------------------------------------------------------------------
// Kernel 2: per-row GRU recurrence + features + layernorm + MLP + argmax.
// One wave (64 threads) per batch row. Lanes mirror mod 32 for the gates.
// __launch_bounds__(64, 2): allow up to 256 real VGPRs (demand ~150) so the
// 96 weight regs + 32 hfull don't round-trip through AGPRs/scratch.
// ---------------------------------------------------------------------------
__global__ __launch_bounds__(64, 2) void k2_head(
    const float* __restrict__ obs, const float* __restrict__ act,
    const float* __restrict__ Whh, const float* __restrict__ bhh,
    const float* __restrict__ lng, const float* __restrict__ lnb,
    const float* __restrict__ W1, const float* __restrict__ b1,
    const float* __restrict__ W2, const float* __restrict__ b2,
    const float* __restrict__ W3, const float* __restrict__ b3,
    const float* __restrict__ gi,
    float* __restrict__ out_wl, float* __restrict__ out_mask)
{
    int b = blockIdx.x;
    int l = threadIdx.x;        // 0..63
    int jj = l & 31;            // gate row index (lanes 32..63 mirror 0..31)

    // preload W_hh rows jj, 32+jj, 64+jj and hidden biases
    float wr[32], wz[32], wn[32];
#pragma unroll
    for (int k = 0; k < 32; ++k) {
        wr[k] = Whh[(0  + jj) * 32 + k];
        wz[k] = Whh[(32 + jj) * 32 + k];
        wn[k] = Whh[(64 + jj) * 32 + k];
    }
    float br = bhh[jj], bz = bhh[32 + jj], bn = bhh[64 + jj];

    float hfull[32];
#pragma unroll
    for (int k = 0; k < 32; ++k) hfull[k] = 0.0f;
    float hown = 0.0f;

    const float* gib = gi + (size_t)b * NSTEP * 96;
    for (int t = 0; t < NSTEP; ++t) {
        float gi_r = gib[t * 96 + jj];
        float gi_z = gib[t * 96 + 32 + jj];
        float gi_n = gib[t * 96 + 64 + jj];
        float ar = br, az = bz, an = bn;
#pragma unroll
        for (int k = 0; k < 32; ++k) {
            ar = fmaf(wr[k], hfull[k], ar);
            az = fmaf(wz[k], hfull[k], az);
            an = fmaf(wn[k], hfull[k], an);
        }
        float r = 1.0f / (1.0f + expf(-(gi_r + ar)));
        float z = 1.0f / (1.0f + expf(-(gi_z + az)));
        float n = tanhf(gi_n + r * an);
        hown = (1.0f - z) * n + z * hown;
#pragma unroll
        for (int k = 0; k < 32; ++k) hfull[k] = __shfl(hown, k, 64);
    }
    // hfull now = h_n (identical on all 64 lanes)

    // ---- features ----
    float o14v[4], o13v[4], o12v[4], o11v[4];
#pragma unroll
    for (int q = 0; q < 4; ++q) {
        int i = l + 64 * q;
        o14v[q] = obs[(size_t)(b * NT + 14) * OBS + i];
        o13v[q] = obs[(size_t)(b * NT + 13) * OBS + i];
        o12v[q] = obs[(size_t)(b * NT + 12) * OBS + i];
        o11v[q] = obs[(size_t)(b * NT + 11) * OBS + i];
    }
    float ap = act[(size_t)(b * NT + 13) * ACTD + l];   // act_prev

    // softmax entropy over obs_t (row 14)
    float m = fmaxf(fmaxf(o14v[0], o14v[1]), fmaxf(o14v[2], o14v[3]));
#pragma unroll
    for (int o = 32; o >= 1; o >>= 1) m = fmaxf(m, __shfl_xor(m, o, 64));
    float e[4];
    float S = 0.0f, so = 0.0f;
#pragma unroll
    for (int q = 0; q < 4; ++q) {
        e[q] = expf(o14v[q] - m);
        S += e[q];
        so += o14v[q];
    }
#pragma unroll
    for (int o = 32; o >= 1; o >>= 1) { S += __shfl_xor(S, o, 64); so += __shfl_xor(so, o, 64); }
    float ent = 0.0f;
#pragma unroll
    for (int q = 0; q < 4; ++q) {
        float p = e[q] / S;
        ent += p * logf(p + 1e-8f);
    }
#pragma unroll
    for (int o = 32; o >= 1; o >>= 1) ent += __shfl_xor(ent, o, 64);
    ent = -ent;

    // rate of change
    float d1 = 0.0f, d2 = 0.0f, d3 = 0.0f;
#pragma unroll
    for (int q = 0; q < 4; ++q) {
        float a = o12v[q] - o11v[q]; d1 = fmaf(a, a, d1);
        a = o13v[q] - o12v[q];       d2 = fmaf(a, a, d2);
        a = o14v[q] - o13v[q];       d3 = fmaf(a, a, d3);
    }
#pragma unroll
    for (int o = 32; o >= 1; o >>= 1) {
        d1 += __shfl_xor(d1, o, 64); d2 += __shfl_xor(d2, o, 64); d3 += __shfl_xor(d3, o, 64);
    }
    float roc = (sqrtf(d1) + sqrtf(d2) + sqrtf(d3)) / 3.0f;

    // correlation
    float sa = ap;
#pragma unroll
    for (int o = 32; o >= 1; o >>= 1) sa += __shfl_xor(sa, o, 64);
    float mu_o = so / 256.0f;
    float mu_a = sa / 256.0f;
    float s_oa = 0.0f, s_oo = 0.0f, s_aa = 0.0f;
#pragma unroll
    for (int q = 0; q < 4; ++q) {
        float ov = o14v[q] - mu_o;
        float av = ((q == 0) ? ap : 0.0f) - mu_a;
        s_oa = fmaf(ov, av, s_oa);
        s_oo = fmaf(ov, ov, s_oo);
        s_aa = fmaf(av, av, s_aa);
    }
#pragma unroll
    for (int o = 32; o >= 1; o >>= 1) {
        s_oa += __shfl_xor(s_oa, o, 64); s_oo += __shfl_xor(s_oo, o, 64); s_aa += __shfl_xor(s_aa, o, 64);
    }
    float corr = s_oa / (sqrtf(s_oo) * sqrtf(s_aa) + 1e-8f);

    // ---- layernorm stats over feats[35] = [ent, roc, corr, h(32)] ----
    float fsum = ent + roc + corr;
#pragma unroll
    for (int k = 0; k < 32; ++k) fsum += hfull[k];
    float mu = fsum / 35.0f;
    float vs = (ent - mu) * (ent - mu) + (roc - mu) * (roc - mu) + (corr - mu) * (corr - mu);
#pragma unroll
    for (int k = 0; k < 32; ++k) { float dd = hfull[k] - mu; vs = fmaf(dd, dd, vs); }
    float inv_sv = 1.0f / sqrtf(vs / 35.0f + 1e-5f);

    // ---- MLP: layernorm fused into W1 dot, no scratch arrays ----
    float x1 = b1[l];
#pragma unroll
    for (int k = 0; k < 35; ++k) {
        float f = (k == 0) ? ent : (k == 1) ? roc : (k == 2) ? corr : hfull[k - 3];
        float fnk = (f - mu) * inv_sv * lng[k] + lnb[k];
        x1 = fmaf(W1[l * 35 + k], fnk, x1);
    }
    x1 = fmaxf(x1, 0.0f);

    float x2 = b2[jj];
#pragma unroll
    for (int k = 0; k < 64; ++k)
        x2 = fmaf(W2[jj * 64 + k], __shfl(x1, k, 64), x2);
    x2 = fmaxf(x2, 0.0f);

    int lr = (l < 14) ? l : 0;
    float lg = b3[lr];
#pragma unroll
    for (int k = 0; k < 32; ++k)
        lg = fmaf(W3[lr * 32 + k], __shfl(x2, k, 64), lg);

    // argmax over 14 logits (first max wins), redundantly on all lanes
    float best = -3.402823466e38f;
    int bi = 0;
#pragma unroll
    for (int j = 0; j < 14; ++j) {
        float v = __shfl(lg, j, 64);
        if (v > best) { best = v; bi = j; }
    }
    int wl = bi + 2;
    if (l == 0) out_wl[b] = (float)wl;
    int s  = (wl - 1) >> 1;
    int ee = wl >> 1;
    if (l < 15) {
        int off = l - 7;
        out_mask[b * 15 + l] = (off >= -s && off <= ee) ? 1.0f : 0.0f;
    }
}

// ---------------------------------------------------------------------------
// Kernel 3: padded_window = concat(obs[:,7:22], act[:,7:22]) * mask
// Pure bandwidth, float4 per thread. Exact grid: 8192*15*80 = 9,830,400.
// ---------------------------------------------------------------------------
__global__ __launch_bounds__(256) void k3_window(
    const float* __restrict__ obs, const float* __restrict__ act,
    const float* __restrict__ mask, float* __restrict__ out_pad)
{
    int idx = blockIdx.x * 256 + threadIdx.x;     // < 9830400
    int bt = idx / 80;
    int k4 = idx - bt * 80;
    int b = bt / 15;
    int t = bt - b * 15;
    float mval = mask[bt];
    float4 v;
    if (k4 < 64) {
        v = *(const float4*)(obs + (size_t)(b * NT + 7 + t) * OBS + k4 * 4);
    } else {
        v = *(const float4*)(act + (size_t)(b * NT + 7 + t) * ACTD + (k4 - 64) * 4);
    }
    v.x *= mval; v.y *= mval; v.z *= mval; v.w *= mval;
    ((float4*)out_pad)[idx] = v;
}

extern "C" void kernel_launch(void* const* d_in, const int* in_sizes, int n_in,
                              void* d_out, int out_size, void* d_ws, size_t ws_size,
                              hipStream_t stream) {
    const float* obs = (const float*)d_in[0];
    const float* act = (const float*)d_in[1];
    const float* Wih = (const float*)d_in[2];
    const float* Whh = (const float*)d_in[3];
    const float* bih = (const float*)d_in[4];
    const float* bhh = (const float*)d_in[5];
    const float* lng = (const float*)d_in[6];
    const float* lnb = (const float*)d_in[7];
    const float* W1  = (const float*)d_in[8];
    const float* b1  = (const float*)d_in[9];
    const float* W2  = (const float*)d_in[10];
    const float* b2  = (const float*)d_in[11];
    const float* W3  = (const float*)d_in[12];
    const float* b3  = (const float*)d_in[13];

    float* out      = (float*)d_out;
    float* out_wl   = out;                      // 8192
    float* out_pad  = out + NB;                 // 39,321,600
    float* out_mask = out + NB + NB * 15 * 320; // 122,880

    // Stage gi (122880*96 floats = 11.8M) inside the padded_window region;
    // it is consumed by k2 before k3 overwrites it.
    float* gi = out_pad;

    k1_gi<<<1920, 64, 0, stream>>>(obs, act, Wih, bih, gi);
    k2_head<<<NB, 64, 0, stream>>>(obs, act, Whh, bhh, lng, lnb,
                                   W1, b1, W2, b2, W3, b3,
                                   gi, out_wl, out_mask);
    k3_window<<<38400, 256, 0, stream>>>(obs, act, out_mask, out_pad);
}

// Round 3
// 743.226 us; speedup vs baseline: 1.5533x; 1.5533x over previous
//
#include <hip/hip_runtime.h>
#include <math.h>

#define OBS 256
#define ACTD 64
#define NB 8192
#define NT 22
#define NSTEP 15

// ---------------------------------------------------------------------------
// Kernel 1: gi = x[122880 x 320] @ W_ih^T[320 x 96] + b_ih, tiled GEMM.
// R5 structure (fixes the R0/R2 latency wall):
//  - Block: 256 threads (4 waves) owns 256 rows x all 96 j. Grid 480 exact.
//  - K-chunked by 32. x chunk staged global->reg->LDS:
//      * global loads COALESCED (8 lanes cover one row's 128B chunk)
//      * LDS word-XOR swizzle lds[row*32 + (k ^ (row&31))] -> compute-phase
//        ds_read_b32 is fully bank-conflict-free (32 distinct banks per
//        half-wave, lane l / l+32 broadcast).
//      * T14 async split: next chunk's global loads issue before compute,
//        vmcnt wait lands at next chunk's LDS write.
//  - Weights NEVER touch LDS: wave-uniform global float2 loads (1 segment
//    per instr, L1-resident 12KB/chunk) -> keeps LDS pipe for x only.
//    LDS demand ~= FMA wall; VALU is ~pure v_fma_f32.
//  - Per-thread tile: 8 rows x 12 j = 96 acc; jg = tid>>5 (8 j-groups of
//    12), lane s = tid&31 owns rows {s+32m}. ~200 VGPRs, bounds(256,2).
//  - Accumulation order per output: bias then k ascending, identical to
//    R0-R4 -> bit-exact (absmax 0.0).
//  - Epilogue: LDS transpose (stride 97, conflict-free) -> coalesced
//    float4 gi stores.
// ---------------------------------------------------------------------------
__global__ __launch_bounds__(256, 2) void k1_gi(
    const float* __restrict__ obs, const float* __restrict__ act,
    const float* __restrict__ Wih, const float* __restrict__ bih,
    float* __restrict__ gi)
{
    __shared__ float lds[8192];   // 32KB: x chunk [256 rows][32 k] swizzled

    const int tid = threadIdx.x;
    const int blk = blockIdx.x;

    // staging mapping: thread loads 8 float4s, rows (tid>>3)+32q, f4 = tid&7
    const int f4o  = (tid & 7) * 4;
    const int srow = tid >> 3;            // 0..31
    int row_base[8];                       // (b*NT + t) per staged row
#pragma unroll
    for (int q = 0; q < 8; ++q) {
        int g = blk * 256 + srow + 32 * q;
        int b = g / 15;
        int t = g - b * 15;
        row_base[q] = b * NT + t;
    }

    // compute mapping
    const int jg = tid >> 5;              // 0..7  -> j tile [jg*12, jg*12+12)
    const int s  = tid & 31;              // row lane: rows s+32m
    const float* wbase = Wih + (size_t)(jg * 12) * 320;

    // prologue: load chunk 0 (kb=0, obs)
    float4 xs[8];
#pragma unroll
    for (int q = 0; q < 8; ++q)
        xs[q] = *(const float4*)(obs + (size_t)row_base[q] * OBS + f4o);

    float acc[8][12];
#pragma unroll
    for (int m = 0; m < 8; ++m)
#pragma unroll
        for (int j = 0; j < 12; ++j)
            acc[m][j] = bih[jg * 12 + j];

#pragma unroll 1
    for (int c = 0; c < 10; ++c) {
        const int kb = 32 * c;
        __syncthreads();                       // prev compute done with LDS
        // stage regs -> LDS with word-XOR swizzle
#pragma unroll
        for (int q = 0; q < 8; ++q) {
            int base = (srow + 32 * q) * 32;
            float v0 = xs[q].x, v1 = xs[q].y, v2 = xs[q].z, v3 = xs[q].w;
            lds[base + ((f4o + 0) ^ srow)] = v0;
            lds[base + ((f4o + 1) ^ srow)] = v1;
            lds[base + ((f4o + 2) ^ srow)] = v2;
            lds[base + ((f4o + 3) ^ srow)] = v3;
        }
        // issue next chunk's loads (latency hides under compute below)
        if (c < 9) {
            int kb2 = kb + 32;
#pragma unroll
            for (int q = 0; q < 8; ++q) {
                const float* src = (kb2 < 256)
                    ? (obs + (size_t)row_base[q] * OBS + kb2 + f4o)
                    : (act + (size_t)row_base[q] * ACTD + (kb2 - 256) + f4o);
                xs[q] = *(const float4*)src;
            }
        }
        __syncthreads();                       // LDS chunk ready
        // compute 32 k values: 2-k steps
#pragma unroll 4
        for (int st = 0; st < 16; ++st) {
            const int k0 = 2 * st;
            // weights: wave-uniform global float2 loads (L1-hot, no LDS)
            float wv[12][2];
#pragma unroll
            for (int j = 0; j < 12; ++j) {
                float2 w2 = *(const float2*)(wbase + (size_t)j * 320 + kb + k0);
                wv[j][0] = w2.x; wv[j][1] = w2.y;
            }
            float xv[8][2];
#pragma unroll
            for (int m = 0; m < 8; ++m) {
                xv[m][0] = lds[(s + 32 * m) * 32 + ((k0 + 0) ^ s)];
                xv[m][1] = lds[(s + 32 * m) * 32 + ((k0 + 1) ^ s)];
            }
#pragma unroll
            for (int m = 0; m < 8; ++m)
#pragma unroll
                for (int j = 0; j < 12; ++j) {
                    acc[m][j] = fmaf(wv[j][0], xv[m][0], acc[m][j]);
                    acc[m][j] = fmaf(wv[j][1], xv[m][1], acc[m][j]);
                }
        }
    }

    // epilogue: 4 transpose passes through LDS (64 rows x 96, stride 97)
#pragma unroll 1
    for (int p = 0; p < 4; ++p) {
        __syncthreads();
#pragma unroll
        for (int mm = 0; mm < 2; ++mm) {
            int m = 2 * p + mm;
            int lr = s + 32 * mm;              // local row 0..63
#pragma unroll
            for (int j = 0; j < 12; ++j)
                lds[lr * 97 + jg * 12 + j] = acc[m][j];
        }
        __syncthreads();
#pragma unroll
        for (int q = 0; q < 6; ++q) {
            int s4 = tid + 256 * q;            // 0..1535
            int r  = s4 / 24;
            int c4 = s4 - r * 24;
            float4 v = make_float4(lds[r * 97 + 4 * c4 + 0],
                                   lds[r * 97 + 4 * c4 + 1],
                                   lds[r * 97 + 4 * c4 + 2],
                                   lds[r * 97 + 4 * c4 + 3]);
            *(float4*)(gi + (size_t)blk * 24576 + p * 6144 + 4 * s4) = v;
        }
    }
}

// ---------------------------------------------------------------------------
// Kernel 2: per-row GRU recurrence + features + layernorm + MLP + argmax.
// One wave (64 threads) per batch row. Lanes mirror mod 32 for the gates.
// ---------------------------------------------------------------------------
__global__ __launch_bounds__(64, 2) void k2_head(
    const float* __restrict__ obs, const float* __restrict__ act,
    const float* __restrict__ Whh, const float* __restrict__ bhh,
    const float* __restrict__ lng, const float* __restrict__ lnb,
    const float* __restrict__ W1, const float* __restrict__ b1,
    const float* __restrict__ W2, const float* __restrict__ b2,
    const float* __restrict__ W3, const float* __restrict__ b3,
    const float* __restrict__ gi,
    float* __restrict__ out_wl, float* __restrict__ out_mask)
{
    int b = blockIdx.x;
    int l = threadIdx.x;        // 0..63
    int jj = l & 31;            // gate row index (lanes 32..63 mirror 0..31)

    float wr[32], wz[32], wn[32];
#pragma unroll
    for (int k = 0; k < 32; ++k) {
        wr[k] = Whh[(0  + jj) * 32 + k];
        wz[k] = Whh[(32 + jj) * 32 + k];
        wn[k] = Whh[(64 + jj) * 32 + k];
    }
    float br = bhh[jj], bz = bhh[32 + jj], bn = bhh[64 + jj];

    float hfull[32];
#pragma unroll
    for (int k = 0; k < 32; ++k) hfull[k] = 0.0f;
    float hown = 0.0f;

    const float* gib = gi + (size_t)b * NSTEP * 96;
    for (int t = 0; t < NSTEP; ++t) {
        float gi_r = gib[t * 96 + jj];
        float gi_z = gib[t * 96 + 32 + jj];
        float gi_n = gib[t * 96 + 64 + jj];
        float ar = br, az = bz, an = bn;
#pragma unroll
        for (int k = 0; k < 32; ++k) {
            ar = fmaf(wr[k], hfull[k], ar);
            az = fmaf(wz[k], hfull[k], az);
            an = fmaf(wn[k], hfull[k], an);
        }
        float r = 1.0f / (1.0f + expf(-(gi_r + ar)));
        float z = 1.0f / (1.0f + expf(-(gi_z + az)));
        float n = tanhf(gi_n + r * an);
        hown = (1.0f - z) * n + z * hown;
#pragma unroll
        for (int k = 0; k < 32; ++k) hfull[k] = __shfl(hown, k, 64);
    }

    // ---- features ----
    float o14v[4], o13v[4], o12v[4], o11v[4];
#pragma unroll
    for (int q = 0; q < 4; ++q) {
        int i = l + 64 * q;
        o14v[q] = obs[(size_t)(b * NT + 14) * OBS + i];
        o13v[q] = obs[(size_t)(b * NT + 13) * OBS + i];
        o12v[q] = obs[(size_t)(b * NT + 12) * OBS + i];
        o11v[q] = obs[(size_t)(b * NT + 11) * OBS + i];
    }
    float ap = act[(size_t)(b * NT + 13) * ACTD + l];

    float m = fmaxf(fmaxf(o14v[0], o14v[1]), fmaxf(o14v[2], o14v[3]));
#pragma unroll
    for (int o = 32; o >= 1; o >>= 1) m = fmaxf(m, __shfl_xor(m, o, 64));
    float e[4];
    float S = 0.0f, so = 0.0f;
#pragma unroll
    for (int q = 0; q < 4; ++q) {
        e[q] = expf(o14v[q] - m);
        S += e[q];
        so += o14v[q];
    }
#pragma unroll
    for (int o = 32; o >= 1; o >>= 1) { S += __shfl_xor(S, o, 64); so += __shfl_xor(so, o, 64); }
    float ent = 0.0f;
#pragma unroll
    for (int q = 0; q < 4; ++q) {
        float p = e[q] / S;
        ent += p * logf(p + 1e-8f);
    }
#pragma unroll
    for (int o = 32; o >= 1; o >>= 1) ent += __shfl_xor(ent, o, 64);
    ent = -ent;

    float d1 = 0.0f, d2 = 0.0f, d3 = 0.0f;
#pragma unroll
    for (int q = 0; q < 4; ++q) {
        float a = o12v[q] - o11v[q]; d1 = fmaf(a, a, d1);
        a = o13v[q] - o12v[q];       d2 = fmaf(a, a, d2);
        a = o14v[q] - o13v[q];       d3 = fmaf(a, a, d3);
    }
#pragma unroll
    for (int o = 32; o >= 1; o >>= 1) {
        d1 += __shfl_xor(d1, o, 64); d2 += __shfl_xor(d2, o, 64); d3 += __shfl_xor(d3, o, 64);
    }
    float roc = (sqrtf(d1) + sqrtf(d2) + sqrtf(d3)) / 3.0f;

    float sa = ap;
#pragma unroll
    for (int o = 32; o >= 1; o >>= 1) sa += __shfl_xor(sa, o, 64);
    float mu_o = so / 256.0f;
    float mu_a = sa / 256.0f;
    float s_oa = 0.0f, s_oo = 0.0f, s_aa = 0.0f;
#pragma unroll
    for (int q = 0; q < 4; ++q) {
        float ov = o14v[q] - mu_o;
        float av = ((q == 0) ? ap : 0.0f) - mu_a;
        s_oa = fmaf(ov, av, s_oa);
        s_oo = fmaf(ov, ov, s_oo);
        s_aa = fmaf(av, av, s_aa);
    }
#pragma unroll
    for (int o = 32; o >= 1; o >>= 1) {
        s_oa += __shfl_xor(s_oa, o, 64); s_oo += __shfl_xor(s_oo, o, 64); s_aa += __shfl_xor(s_aa, o, 64);
    }
    float corr = s_oa / (sqrtf(s_oo) * sqrtf(s_aa) + 1e-8f);

    float fsum = ent + roc + corr;
#pragma unroll
    for (int k = 0; k < 32; ++k) fsum += hfull[k];
    float mu = fsum / 35.0f;
    float vs = (ent - mu) * (ent - mu) + (roc - mu) * (roc - mu) + (corr - mu) * (corr - mu);
#pragma unroll
    for (int k = 0; k < 32; ++k) { float dd = hfull[k] - mu; vs = fmaf(dd, dd, vs); }
    float inv_sv = 1.0f / sqrtf(vs / 35.0f + 1e-5f);

    float x1 = b1[l];
#pragma unroll
    for (int k = 0; k < 35; ++k) {
        float f = (k == 0) ? ent : (k == 1) ? roc : (k == 2) ? corr : hfull[k - 3];
        float fnk = (f - mu) * inv_sv * lng[k] + lnb[k];
        x1 = fmaf(W1[l * 35 + k], fnk, x1);
    }
    x1 = fmaxf(x1, 0.0f);

    float x2 = b2[jj];
#pragma unroll
    for (int k = 0; k < 64; ++k)
        x2 = fmaf(W2[jj * 64 + k], __shfl(x1, k, 64), x2);
    x2 = fmaxf(x2, 0.0f);

    int lr = (l < 14) ? l : 0;
    float lg = b3[lr];
#pragma unroll
    for (int k = 0; k < 32; ++k)
        lg = fmaf(W3[lr * 32 + k], __shfl(x2, k, 64), lg);

    float best = -3.402823466e38f;
    int bi = 0;
#pragma unroll
    for (int j = 0; j < 14; ++j) {
        float v = __shfl(lg, j, 64);
        if (v > best) { best = v; bi = j; }
    }
    int wl = bi + 2;
    if (l == 0) out_wl[b] = (float)wl;
    int s思  = (wl - 1) >> 1;
    int ee = wl >> 1;
    if (l < 15) {
        int off = l - 7;
        out_mask[b * 15 + l] = (off >= -s思 && off <= ee) ? 1.0f : 0.0f;
    }
}

// ---------------------------------------------------------------------------
// Kernel 3: padded_window = concat(obs[:,7:22], act[:,7:22]) * mask
// ---------------------------------------------------------------------------
__global__ __launch_bounds__(256) void k3_window(
    const float* __restrict__ obs, const float* __restrict__ act,
    const float* __restrict__ mask, float* __restrict__ out_pad)
{
    int idx = blockIdx.x * 256 + threadIdx.x;     // < 9830400
    int bt = idx / 80;
    int k4 = idx - bt * 80;
    int b = bt / 15;
    int t = bt - b * 15;
    float mval = mask[bt];
    float4 v;
    if (k4 < 64) {
        v = *(const float4*)(obs + (size_t)(b * NT + 7 + t) * OBS + k4 * 4);
    } else {
        v = *(const float4*)(act + (size_t)(b * NT + 7 + t) * ACTD + (k4 - 64) * 4);
    }
    v.x *= mval; v.y *= mval; v.z *= mval; v.w *= mval;
    ((float4*)out_pad)[idx] = v;
}

extern "C" void kernel_launch(void* const* d_in, const int* in_sizes, int n_in,
                              void* d_out, int out_size, void* d_ws, size_t ws_size,
                              hipStream_t stream) {
    const float* obs = (const float*)d_in[0];
    const float* act = (const float*)d_in[1];
    const float* Wih = (const float*)d_in[2];
    const float* Whh = (const float*)d_in[3];
    const float* bih = (const float*)d_in[4];
    const float* bhh = (const float*)d_in[5];
    const float* lng = (const float*)d_in[6];
    const float* lnb = (const float*)d_in[7];
    const float* W1  = (const float*)d_in[8];
    const float* b1  = (const float*)d_in[9];
    const float* W2  = (const float*)d_in[10];
    const float* b2  = (const float*)d_in[11];
    const float* W3  = (const float*)d_in[12];
    const float* b3  = (const float*)d_in[13];

    float* out      = (float*)d_out;
    float* out_wl   = out;                      // 8192
    float* out_pad  = out + NB;                 // 39,321,600
    float* out_mask = out + NB + NB * 15 * 320; // 122,880

    // Stage gi (122880*96 floats = 11.8M) inside the padded_window region;
    // it is consumed by k2 before k3 overwrites it.
    float* gi = out_pad;

    k1_gi<<<480, 256, 0, stream>>>(obs, act, Wih, bih, gi);
    k2_head<<<NB, 64, 0, stream>>>(obs, act, Whh, bhh, lng, lnb,
                                   W1, b1, W2, b2, W3, b3,
                                   gi, out_wl, out_mask);
    k3_window<<<38400, 256, 0, stream>>>(obs, act, out_mask, out_pad);
}

// Round 4
// 660.158 us; speedup vs baseline: 1.7488x; 1.1258x over previous
//
#include <hip/hip_runtime.h>
#include <math.h>

#define OBS 256
#define ACTD 64
#define NB 8192
#define NT 22
#define NSTEP 15

// ---------------------------------------------------------------------------
// Kernel 1: gi = x[122880 x 320] @ W_ih^T[320 x 96] + b_ih, tiled GEMM.
// R5 structure, R6 fix: __launch_bounds__(256, 1).
//   R5 shipped with (256,2) -> compiler capped at 128 VGPRs vs ~190 demand
//   -> ~60 regs spilled to scratch in the K-loop -> WRITE_SIZE 688 MB
//   (641 MB spill) and 364 us. With a 512 cap the allocator takes ~200,
//   runtime occupancy is still 2 waves/SIMD (8 waves/CU), zero spill.
//  - Block: 256 threads (4 waves) owns 256 rows x all 96 j. Grid 480 exact.
//  - K-chunked by 32. x staged global->reg->LDS, word-XOR swizzle
//    (compute-phase ds_read_b32 bank-conflict-free).
//  - Weights: global float2 loads (2 addr/wave, L1-hot), never LDS.
//  - Accumulation order per output: bias then k ascending, identical to
//    R0-R5 -> bit-exact (absmax 0.0).
// ---------------------------------------------------------------------------
__global__ __launch_bounds__(256, 1) void k1_gi(
    const float* __restrict__ obs, const float* __restrict__ act,
    const float* __restrict__ Wih, const float* __restrict__ bih,
    float* __restrict__ gi)
{
    __shared__ float lds[8192];   // 32KB: x chunk [256 rows][32 k] swizzled

    const int tid = threadIdx.x;
    const int blk = blockIdx.x;

    // staging mapping: thread loads 8 float4s, rows (tid>>3)+32q, f4 = tid&7
    const int f4o  = (tid & 7) * 4;
    const int srow = tid >> 3;            // 0..31
    int row_base[8];                       // (b*NT + t) per staged row
#pragma unroll
    for (int q = 0; q < 8; ++q) {
        int g = blk * 256 + srow + 32 * q;
        int b = g / 15;
        int t = g - b * 15;
        row_base[q] = b * NT + t;
    }

    // compute mapping
    const int jg = tid >> 5;              // 0..7  -> j tile [jg*12, jg*12+12)
    const int s  = tid & 31;              // row lane: rows s+32m
    const float* wbase = Wih + (size_t)(jg * 12) * 320;

    // prologue: load chunk 0 (kb=0, obs)
    float4 xs[8];
#pragma unroll
    for (int q = 0; q < 8; ++q)
        xs[q] = *(const float4*)(obs + (size_t)row_base[q] * OBS + f4o);

    float acc[8][12];
#pragma unroll
    for (int m = 0; m < 8; ++m)
#pragma unroll
        for (int j = 0; j < 12; ++j)
            acc[m][j] = bih[jg * 12 + j];

#pragma unroll 1
    for (int c = 0; c < 10; ++c) {
        const int kb = 32 * c;
        __syncthreads();                       // prev compute done with LDS
        // stage regs -> LDS with word-XOR swizzle
#pragma unroll
        for (int q = 0; q < 8; ++q) {
            int base = (srow + 32 * q) * 32;
            float v0 = xs[q].x, v1 = xs[q].y, v2 = xs[q].z, v3 = xs[q].w;
            lds[base + ((f4o + 0) ^ srow)] = v0;
            lds[base + ((f4o + 1) ^ srow)] = v1;
            lds[base + ((f4o + 2) ^ srow)] = v2;
            lds[base + ((f4o + 3) ^ srow)] = v3;
        }
        // issue next chunk's loads (latency hides under compute below)
        if (c < 9) {
            int kb2 = kb + 32;
#pragma unroll
            for (int q = 0; q < 8; ++q) {
                const float* src = (kb2 < 256)
                    ? (obs + (size_t)row_base[q] * OBS + kb2 + f4o)
                    : (act + (size_t)row_base[q] * ACTD + (kb2 - 256) + f4o);
                xs[q] = *(const float4*)src;
            }
        }
        __syncthreads();                       // LDS chunk ready
        // compute 32 k values: 2-k steps
#pragma unroll 4
        for (int st = 0; st < 16; ++st) {
            const int k0 = 2 * st;
            float wv[12][2];
#pragma unroll
            for (int j = 0; j < 12; ++j) {
                float2 w2 = *(const float2*)(wbase + (size_t)j * 320 + kb + k0);
                wv[j][0] = w2.x; wv[j][1] = w2.y;
            }
            float xv[8][2];
#pragma unroll
            for (int m = 0; m < 8; ++m) {
                xv[m][0] = lds[(s + 32 * m) * 32 + ((k0 + 0) ^ s)];
                xv[m][1] = lds[(s + 32 * m) * 32 + ((k0 + 1) ^ s)];
            }
#pragma unroll
            for (int m = 0; m < 8; ++m)
#pragma unroll
                for (int j = 0; j < 12; ++j) {
                    acc[m][j] = fmaf(wv[j][0], xv[m][0], acc[m][j]);
                    acc[m][j] = fmaf(wv[j][1], xv[m][1], acc[m][j]);
                }
        }
    }

    // epilogue: 4 transpose passes through LDS (64 rows x 96, stride 97)
#pragma unroll 1
    for (int p = 0; p < 4; ++p) {
        __syncthreads();
#pragma unroll
        for (int mm = 0; mm < 2; ++mm) {
            int m = 2 * p + mm;
            int lr = s + 32 * mm;              // local row 0..63
#pragma unroll
            for (int j = 0; j < 12; ++j)
                lds[lr * 97 + jg * 12 + j] = acc[m][j];
        }
        __syncthreads();
#pragma unroll
        for (int q = 0; q < 6; ++q) {
            int s4 = tid + 256 * q;            // 0..1535
            int r  = s4 / 24;
            int c4 = s4 - r * 24;
            float4 v = make_float4(lds[r * 97 + 4 * c4 + 0],
                                   lds[r * 97 + 4 * c4 + 1],
                                   lds[r * 97 + 4 * c4 + 2],
                                   lds[r * 97 + 4 * c4 + 3]);
            *(float4*)(gi + (size_t)blk * 24576 + p * 6144 + 4 * s4) = v;
        }
    }
}

// ---------------------------------------------------------------------------
// Kernel 2: per-row GRU recurrence + features + layernorm + MLP + argmax.
// One wave (64 threads) per batch row. Lanes mirror mod 32 for the gates.
// ---------------------------------------------------------------------------
__global__ __launch_bounds__(64, 2) void k2_head(
    const float* __restrict__ obs, const float* __restrict__ act,
    const float* __restrict__ Whh, const float* __restrict__ bhh,
    const float* __restrict__ lng, const float* __restrict__ lnb,
    const float* __restrict__ W1, const float* __restrict__ b1,
    const float* __restrict__ W2, const float* __restrict__ b2,
    const float* __restrict__ W3, const float* __restrict__ b3,
    const float* __restrict__ gi,
    float* __restrict__ out_wl, float* __restrict__ out_mask)
{
    int b = blockIdx.x;
    int l = threadIdx.x;        // 0..63
    int jj = l & 31;            // gate row index (lanes 32..63 mirror 0..31)

    float wr[32], wz[32], wn[32];
#pragma unroll
    for (int k = 0; k < 32; ++k) {
        wr[k] = Whh[(0  + jj) * 32 + k];
        wz[k] = Whh[(32 + jj) * 32 + k];
        wn[k] = Whh[(64 + jj) * 32 + k];
    }
    float br = bhh[jj], bz = bhh[32 + jj], bn = bhh[64 + jj];

    float hfull[32];
#pragma unroll
    for (int k = 0; k < 32; ++k) hfull[k] = 0.0f;
    float hown = 0.0f;

    const float* gib = gi + (size_t)b * NSTEP * 96;
    for (int t = 0; t < NSTEP; ++t) {
        float gi_r = gib[t * 96 + jj];
        float gi_z = gib[t * 96 + 32 + jj];
        float gi_n = gib[t * 96 + 64 + jj];
        float ar = br, az = bz, an = bn;
#pragma unroll
        for (int k = 0; k < 32; ++k) {
            ar = fmaf(wr[k], hfull[k], ar);
            az = fmaf(wz[k], hfull[k], az);
            an = fmaf(wn[k], hfull[k], an);
        }
        float r = 1.0f / (1.0f + expf(-(gi_r + ar)));
        float z = 1.0f / (1.0f + expf(-(gi_z + az)));
        float n = tanhf(gi_n + r * an);
        hown = (1.0f - z) * n + z * hown;
#pragma unroll
        for (int k = 0; k < 32; ++k) hfull[k] = __shfl(hown, k, 64);
    }

    // ---- features ----
    float o14v[4], o13v[4], o12v[4], o11v[4];
#pragma unroll
    for (int q = 0; q < 4; ++q) {
        int i = l + 64 * q;
        o14v[q] = obs[(size_t)(b * NT + 14) * OBS + i];
        o13v[q] = obs[(size_t)(b * NT + 13) * OBS + i];
        o12v[q] = obs[(size_t)(b * NT + 12) * OBS + i];
        o11v[q] = obs[(size_t)(b * NT + 11) * OBS + i];
    }
    float ap = act[(size_t)(b * NT + 13) * ACTD + l];

    float m = fmaxf(fmaxf(o14v[0], o14v[1]), fmaxf(o14v[2], o14v[3]));
#pragma unroll
    for (int o = 32; o >= 1; o >>= 1) m = fmaxf(m, __shfl_xor(m, o, 64));
    float e[4];
    float S = 0.0f, so = 0.0f;
#pragma unroll
    for (int q = 0; q < 4; ++q) {
        e[q] = expf(o14v[q] - m);
        S += e[q];
        so += o14v[q];
    }
#pragma unroll
    for (int o = 32; o >= 1; o >>= 1) { S += __shfl_xor(S, o, 64); so += __shfl_xor(so, o, 64); }
    float ent = 0.0f;
#pragma unroll
    for (int q = 0; q < 4; ++q) {
        float p = e[q] / S;
        ent += p * logf(p + 1e-8f);
    }
#pragma unroll
    for (int o = 32; o >= 1; o >>= 1) ent += __shfl_xor(ent, o, 64);
    ent = -ent;

    float d1 = 0.0f, d2 = 0.0f, d3 = 0.0f;
#pragma unroll
    for (int q = 0; q < 4; ++q) {
        float a = o12v[q] - o11v[q]; d1 = fmaf(a, a, d1);
        a = o13v[q] - o12v[q];       d2 = fmaf(a, a, d2);
        a = o14v[q] - o13v[q];       d3 = fmaf(a, a, d3);
    }
#pragma unroll
    for (int o = 32; o >= 1; o >>= 1) {
        d1 += __shfl_xor(d1, o, 64); d2 += __shfl_xor(d2, o, 64); d3 += __shfl_xor(d3, o, 64);
    }
    float roc = (sqrtf(d1) + sqrtf(d2) + sqrtf(d3)) / 3.0f;

    float sa = ap;
#pragma unroll
    for (int o = 32; o >= 1; o >>= 1) sa += __shfl_xor(sa, o, 64);
    float mu_o = so / 256.0f;
    float mu_a = sa / 256.0f;
    float s_oa = 0.0f, s_oo = 0.0f, s_aa = 0.0f;
#pragma unroll
    for (int q = 0; q < 4; ++q) {
        float ov = o14v[q] - mu_o;
        float av = ((q == 0) ? ap : 0.0f) - mu_a;
        s_oa = fmaf(ov, av, s_oa);
        s_oo = fmaf(ov, ov, s_oo);
        s_aa = fmaf(av, av, s_aa);
    }
#pragma unroll
    for (int o = 32; o >= 1; o >>= 1) {
        s_oa += __shfl_xor(s_oa, o, 64); s_oo += __shfl_xor(s_oo, o, 64); s_aa += __shfl_xor(s_aa, o, 64);
    }
    float corr = s_oa / (sqrtf(s_oo) * sqrtf(s_aa) + 1e-8f);

    float fsum = ent + roc + corr;
#pragma unroll
    for (int k = 0; k < 32; ++k) fsum += hfull[k];
    float mu = fsum / 35.0f;
    float vs = (ent - mu) * (ent - mu) + (roc - mu) * (roc - mu) + (corr - mu) * (corr - mu);
#pragma unroll
    for (int k = 0; k < 32; ++k) { float dd = hfull[k] - mu; vs = fmaf(dd, dd, vs); }
    float inv_sv = 1.0f / sqrtf(vs / 35.0f + 1e-5f);

    float x1 = b1[l];
#pragma unroll
    for (int k = 0; k < 35; ++k) {
        float f = (k == 0) ? ent : (k == 1) ? roc : (k == 2) ? corr : hfull[k - 3];
        float fnk = (f - mu) * inv_sv * lng[k] + lnb[k];
        x1 = fmaf(W1[l * 35 + k], fnk, x1);
    }
    x1 = fmaxf(x1, 0.0f);

    float x2 = b2[jj];
#pragma unroll
    for (int k = 0; k < 64; ++k)
        x2 = fmaf(W2[jj * 64 + k], __shfl(x1, k, 64), x2);
    x2 = fmaxf(x2, 0.0f);

    int lr = (l < 14) ? l : 0;
    float lg = b3[lr];
#pragma unroll
    for (int k = 0; k < 32; ++k)
        lg = fmaf(W3[lr * 32 + k], __shfl(x2, k, 64), lg);

    float best = -3.402823466e38f;
    int bi = 0;
#pragma unroll
    for (int j = 0; j < 14; ++j) {
        float v = __shfl(lg, j, 64);
        if (v > best) { best = v; bi = j; }
    }
    int wl = bi + 2;
    if (l == 0) out_wl[b] = (float)wl;
    int ss = (wl - 1) >> 1;
    int ee = wl >> 1;
    if (l < 15) {
        int off = l - 7;
        out_mask[b * 15 + l] = (off >= -ss && off <= ee) ? 1.0f : 0.0f;
    }
}

// ---------------------------------------------------------------------------
// Kernel 3: padded_window = concat(obs[:,7:22], act[:,7:22]) * mask
// ---------------------------------------------------------------------------
__global__ __launch_bounds__(256) void k3_window(
    const float* __restrict__ obs, const float* __restrict__ act,
    const float* __restrict__ mask, float* __restrict__ out_pad)
{
    int idx = blockIdx.x * 256 + threadIdx.x;     // < 9830400
    int bt = idx / 80;
    int k4 = idx - bt * 80;
    int b = bt / 15;
    int t = bt - b * 15;
    float mval = mask[bt];
    float4 v;
    if (k4 < 64) {
        v = *(const float4*)(obs + (size_t)(b * NT + 7 + t) * OBS + k4 * 4);
    } else {
        v = *(const float4*)(act + (size_t)(b * NT + 7 + t) * ACTD + (k4 - 64) * 4);
    }
    v.x *= mval; v.y *= mval; v.z *= mval; v.w *= mval;
    ((float4*)out_pad)[idx] = v;
}

extern "C" void kernel_launch(void* const* d_in, const int* in_sizes, int n_in,
                              void* d_out, int out_size, void* d_ws, size_t ws_size,
                              hipStream_t stream) {
    const float* obs = (const float*)d_in[0];
    const float* act = (const float*)d_in[1];
    const float* Wih = (const float*)d_in[2];
    const float* Whh = (const float*)d_in[3];
    const float* bih = (const float*)d_in[4];
    const float* bhh = (const float*)d_in[5];
    const float* lng = (const float*)d_in[6];
    const float* lnb = (const float*)d_in[7];
    const float* W1  = (const float*)d_in[8];
    const float* b1  = (const float*)d_in[9];
    const float* W2  = (const float*)d_in[10];
    const float* b2  = (const float*)d_in[11];
    const float* W3  = (const float*)d_in[12];
    const float* b3  = (const float*)d_in[13];

    float* out      = (float*)d_out;
    float* out_wl   = out;                      // 8192
    float* out_pad  = out + NB;                 // 39,321,600
    float* out_mask = out + NB + NB * 15 * 320; // 122,880

    // Stage gi (122880*96 floats = 11.8M) inside the padded_window region;
    // it is consumed by k2 before k3 overwrites it.
    float* gi = out_pad;

    k1_gi<<<480, 256, 0, stream>>>(obs, act, Wih, bih, gi);
    k2_head<<<NB, 64, 0, stream>>>(obs, act, Whh, bhh, lng, lnb,
                                   W1, b1, W2, b2, W3, b3,
                                   gi, out_wl, out_mask);
    k3_window<<<38400, 256, 0, stream>>>(obs, act, out_mask, out_pad);
}

// Round 5
// 631.130 us; speedup vs baseline: 1.8292x; 1.0460x over previous
//
#include <hip/hip_runtime.h>
#include <math.h>

#define OBS 256
#define ACTD 64
#define NB 8192
#define NT 22
#define NSTEP 15

// ---------------------------------------------------------------------------
// Kernel 1: gi = x[122880 x 320] @ W_ih^T[320 x 96] + b_ih, tiled GEMM.
// R7 fix: inner-loop unroll 1 (was 4). The unroll-4 body kept 4x(24 wv +
// 16 xv) = 160 temporaries live on top of 96 acc + 32 staging -> ~300 reg
// demand vs the 256 arch-VGPR/wave ceiling -> allocator spilled acc[] to
// scratch every chunk (WRITE_SIZE 497 MB, 450 MB spill, k1 = 304 us).
// Unroll 1 live set ~200 regs: fits, zero spill, 96 indep FMAs/iter ILP.
//  - Block: 256 threads (4 waves) owns 256 rows x all 96 j. Grid 480 exact.
//  - K-chunked by 32. x staged global->reg->LDS, word-XOR swizzle
//    (compute-phase ds_read_b32 bank-conflict-free).
//  - Weights: global float2 loads (2 segments/wave instr, L1-hot), no LDS.
//  - Accumulation order per output: bias then k ascending, identical to
//    R0-R6 -> bit-exact (absmax 0.0).
// ---------------------------------------------------------------------------
__global__ __launch_bounds__(256, 1) void k1_gi(
    const float* __restrict__ obs, const float* __restrict__ act,
    const float* __restrict__ Wih, const float* __restrict__ bih,
    float* __restrict__ gi)
{
    __shared__ float lds[8192];   // 32KB: x chunk [256 rows][32 k] swizzled

    const int tid = threadIdx.x;
    const int blk = blockIdx.x;

    // staging mapping: thread loads 8 float4s, rows (tid>>3)+32q, f4 = tid&7
    const int f4o  = (tid & 7) * 4;
    const int srow = tid >> 3;            // 0..31
    int row_base[8];                       // (b*NT + t) per staged row
#pragma unroll
    for (int q = 0; q < 8; ++q) {
        int g = blk * 256 + srow + 32 * q;
        int b = g / 15;
        int t = g - b * 15;
        row_base[q] = b * NT + t;
    }

    // compute mapping
    const int jg = tid >> 5;              // 0..7  -> j tile [jg*12, jg*12+12)
    const int s  = tid & 31;              // row lane: rows s+32m
    const float* wbase = Wih + (size_t)(jg * 12) * 320;

    // prologue: load chunk 0 (kb=0, obs)
    float4 xs[8];
#pragma unroll
    for (int q = 0; q < 8; ++q)
        xs[q] = *(const float4*)(obs + (size_t)row_base[q] * OBS + f4o);

    float acc[8][12];
#pragma unroll
    for (int m = 0; m < 8; ++m)
#pragma unroll
        for (int j = 0; j < 12; ++j)
            acc[m][j] = bih[jg * 12 + j];

#pragma unroll 1
    for (int c = 0; c < 10; ++c) {
        const int kb = 32 * c;
        __syncthreads();                       // prev compute done with LDS
        // stage regs -> LDS with word-XOR swizzle
#pragma unroll
        for (int q = 0; q < 8; ++q) {
            int base = (srow + 32 * q) * 32;
            float v0 = xs[q].x, v1 = xs[q].y, v2 = xs[q].z, v3 = xs[q].w;
            lds[base + ((f4o + 0) ^ srow)] = v0;
            lds[base + ((f4o + 1) ^ srow)] = v1;
            lds[base + ((f4o + 2) ^ srow)] = v2;
            lds[base + ((f4o + 3) ^ srow)] = v3;
        }
        // issue next chunk's loads (latency hides under compute below)
        if (c < 9) {
            int kb2 = kb + 32;
#pragma unroll
            for (int q = 0; q < 8; ++q) {
                const float* src = (kb2 < 256)
                    ? (obs + (size_t)row_base[q] * OBS + kb2 + f4o)
                    : (act + (size_t)row_base[q] * ACTD + (kb2 - 256) + f4o);
                xs[q] = *(const float4*)src;
            }
        }
        __syncthreads();                       // LDS chunk ready
        // compute 32 k values in 2-k steps; unroll 1 keeps live set ~200 reg
#pragma unroll 1
        for (int st = 0; st < 16; ++st) {
            const int k0 = 2 * st;
            float wv[12][2];
#pragma unroll
            for (int j = 0; j < 12; ++j) {
                float2 w2 = *(const float2*)(wbase + (size_t)j * 320 + kb + k0);
                wv[j][0] = w2.x; wv[j][1] = w2.y;
            }
            float xv[8][2];
#pragma unroll
            for (int m = 0; m < 8; ++m) {
                xv[m][0] = lds[(s + 32 * m) * 32 + ((k0 + 0) ^ s)];
                xv[m][1] = lds[(s + 32 * m) * 32 + ((k0 + 1) ^ s)];
            }
#pragma unroll
            for (int m = 0; m < 8; ++m)
#pragma unroll
                for (int j = 0; j < 12; ++j) {
                    acc[m][j] = fmaf(wv[j][0], xv[m][0], acc[m][j]);
                    acc[m][j] = fmaf(wv[j][1], xv[m][1], acc[m][j]);
                }
        }
    }

    // epilogue: 4 transpose passes through LDS (64 rows x 96, stride 97)
#pragma unroll 1
    for (int p = 0; p < 4; ++p) {
        __syncthreads();
#pragma unroll
        for (int mm = 0; mm < 2; ++mm) {
            int m = 2 * p + mm;
            int lr = s + 32 * mm;              // local row 0..63
#pragma unroll
            for (int j = 0; j < 12; ++j)
                lds[lr * 97 + jg * 12 + j] = acc[m][j];
        }
        __syncthreads();
#pragma unroll
        for (int q = 0; q < 6; ++q) {
            int s4 = tid + 256 * q;            // 0..1535
            int r  = s4 / 24;
            int c4 = s4 - r * 24;
            float4 v = make_float4(lds[r * 97 + 4 * c4 + 0],
                                   lds[r * 97 + 4 * c4 + 1],
                                   lds[r * 97 + 4 * c4 + 2],
                                   lds[r * 97 + 4 * c4 + 3]);
            *(float4*)(gi + (size_t)blk * 24576 + p * 6144 + 4 * s4) = v;
        }
    }
}

// ---------------------------------------------------------------------------
// Kernel 2: per-row GRU recurrence + features + layernorm + MLP + argmax.
// One wave (64 threads) per batch row. Lanes mirror mod 32 for the gates.
// ---------------------------------------------------------------------------
__global__ __launch_bounds__(64, 2) void k2_head(
    const float* __restrict__ obs, const float* __restrict__ act,
    const float* __restrict__ Whh, const float* __restrict__ bhh,
    const float* __restrict__ lng, const float* __restrict__ lnb,
    const float* __restrict__ W1, const float* __restrict__ b1,
    const float* __restrict__ W2, const float* __restrict__ b2,
    const float* __restrict__ W3, const float* __restrict__ b3,
    const float* __restrict__ gi,
    float* __restrict__ out_wl, float* __restrict__ out_mask)
{
    int b = blockIdx.x;
    int l = threadIdx.x;        // 0..63
    int jj = l & 31;            // gate row index (lanes 32..63 mirror 0..31)

    float wr[32], wz[32], wn[32];
#pragma unroll
    for (int k = 0; k < 32; ++k) {
        wr[k] = Whh[(0  + jj) * 32 + k];
        wz[k] = Whh[(32 + jj) * 32 + k];
        wn[k] = Whh[(64 + jj) * 32 + k];
    }
    float br = bhh[jj], bz = bhh[32 + jj], bn = bhh[64 + jj];

    float hfull[32];
#pragma unroll
    for (int k = 0; k < 32; ++k) hfull[k] = 0.0f;
    float hown = 0.0f;

    const float* gib = gi + (size_t)b * NSTEP * 96;
    for (int t = 0; t < NSTEP; ++t) {
        float gi_r = gib[t * 96 + jj];
        float gi_z = gib[t * 96 + 32 + jj];
        float gi_n = gib[t * 96 + 64 + jj];
        float ar = br, az = bz, an = bn;
#pragma unroll
        for (int k = 0; k < 32; ++k) {
            ar = fmaf(wr[k], hfull[k], ar);
            az = fmaf(wz[k], hfull[k], az);
            an = fmaf(wn[k], hfull[k], an);
        }
        float r = 1.0f / (1.0f + expf(-(gi_r + ar)));
        float z = 1.0f / (1.0f + expf(-(gi_z + az)));
        float n = tanhf(gi_n + r * an);
        hown = (1.0f - z) * n + z * hown;
#pragma unroll
        for (int k = 0; k < 32; ++k) hfull[k] = __shfl(hown, k, 64);
    }

    // ---- features ----
    float o14v[4], o13v[4], o12v[4], o11v[4];
#pragma unroll
    for (int q = 0; q < 4; ++q) {
        int i = l + 64 * q;
        o14v[q] = obs[(size_t)(b * NT + 14) * OBS + i];
        o13v[q] = obs[(size_t)(b * NT + 13) * OBS + i];
        o12v[q] = obs[(size_t)(b * NT + 12) * OBS + i];
        o11v[q] = obs[(size_t)(b * NT + 11) * OBS + i];
    }
    float ap = act[(size_t)(b * NT + 13) * ACTD + l];

    float m = fmaxf(fmaxf(o14v[0], o14v[1]), fmaxf(o14v[2], o14v[3]));
#pragma unroll
    for (int o = 32; o >= 1; o >>= 1) m = fmaxf(m, __shfl_xor(m, o, 64));
    float e[4];
    float S = 0.0f, so = 0.0f;
#pragma unroll
    for (int q = 0; q < 4; ++q) {
        e[q] = expf(o14v[q] - m);
        S += e[q];
        so += o14v[q];
    }
#pragma unroll
    for (int o = 32; o >= 1; o >>= 1) { S += __shfl_xor(S, o, 64); so += __shfl_xor(so, o, 64); }
    float ent = 0.0f;
#pragma unroll
    for (int q = 0; q < 4; ++q) {
        float p = e[q] / S;
        ent += p * logf(p + 1e-8f);
    }
#pragma unroll
    for (int o = 32; o >= 1; o >>= 1) ent += __shfl_xor(ent, o, 64);
    ent = -ent;

    float d1 = 0.0f, d2 = 0.0f, d3 = 0.0f;
#pragma unroll
    for (int q = 0; q < 4; ++q) {
        float a = o12v[q] - o11v[q]; d1 = fmaf(a, a, d1);
        a = o13v[q] - o12v[q];       d2 = fmaf(a, a, d2);
        a = o14v[q] - o13v[q];       d3 = fmaf(a, a, d3);
    }
#pragma unroll
    for (int o = 32; o >= 1; o >>= 1) {
        d1 += __shfl_xor(d1, o, 64); d2 += __shfl_xor(d2, o, 64); d3 += __shfl_xor(d3, o, 64);
    }
    float roc = (sqrtf(d1) + sqrtf(d2) + sqrtf(d3)) / 3.0f;

    float sa = ap;
#pragma unroll
    for (int o = 32; o >= 1; o >>= 1) sa += __shfl_xor(sa, o, 64);
    float mu_o = so / 256.0f;
    float mu_a = sa / 256.0f;
    float s_oa = 0.0f, s_oo = 0.0f, s_aa = 0.0f;
#pragma unroll
    for (int q = 0; q < 4; ++q) {
        float ov = o14v[q] - mu_o;
        float av = ((q == 0) ? ap : 0.0f) - mu_a;
        s_oa = fmaf(ov, av, s_oa);
        s_oo = fmaf(ov, ov, s_oo);
        s_aa = fmaf(av, av, s_aa);
    }
#pragma unroll
    for (int o = 32; o >= 1; o >>= 1) {
        s_oa += __shfl_xor(s_oa, o, 64); s_oo += __shfl_xor(s_oo, o, 64); s_aa += __shfl_xor(s_aa, o, 64);
    }
    float corr = s_oa / (sqrtf(s_oo) * sqrtf(s_aa) + 1e-8f);

    float fsum = ent + roc + corr;
#pragma unroll
    for (int k = 0; k < 32; ++k) fsum += hfull[k];
    float mu = fsum / 35.0f;
    float vs = (ent - mu) * (ent - mu) + (roc - mu) * (roc - mu) + (corr - mu) * (corr - mu);
#pragma unroll
    for (int k = 0; k < 32; ++k) { float dd = hfull[k] - mu; vs = fmaf(dd, dd, vs); }
    float inv_sv = 1.0f / sqrtf(vs / 35.0f + 1e-5f);

    float x1 = b1[l];
#pragma unroll
    for (int k = 0; k < 35; ++k) {
        float f = (k == 0) ? ent : (k == 1) ? roc : (k == 2) ? corr : hfull[k - 3];
        float fnk = (f - mu) * inv_sv * lng[k] + lnb[k];
        x1 = fmaf(W1[l * 35 + k], fnk, x1);
    }
    x1 = fmaxf(x1, 0.0f);

    float x2 = b2[jj];
#pragma unroll
    for (int k = 0; k < 64; ++k)
        x2 = fmaf(W2[jj * 64 + k], __shfl(x1, k, 64), x2);
    x2 = fmaxf(x2, 0.0f);

    int lr = (l < 14) ? l : 0;
    float lg = b3[lr];
#pragma unroll
    for (int k = 0; k < 32; ++k)
        lg = fmaf(W3[lr * 32 + k], __shfl(x2, k, 64), lg);

    float best = -3.402823466e38f;
    int bi = 0;
#pragma unroll
    for (int j = 0; j < 14; ++j) {
        float v = __shfl(lg, j, 64);
        if (v > best) { best = v; bi = j; }
    }
    int wl = bi + 2;
    if (l == 0) out_wl[b] = (float)wl;
    int ss = (wl - 1) >> 1;
    int ee = wl >> 1;
    if (l < 15) {
        int off = l - 7;
        out_mask[b * 15 + l] = (off >= -ss && off <= ee) ? 1.0f : 0.0f;
    }
}

// ---------------------------------------------------------------------------
// Kernel 3: padded_window = concat(obs[:,7:22], act[:,7:22]) * mask
// ---------------------------------------------------------------------------
__global__ __launch_bounds__(256) void k3_window(
    const float* __restrict__ obs, const float* __restrict__ act,
    const float* __restrict__ mask, float* __restrict__ out_pad)
{
    int idx = blockIdx.x * 256 + threadIdx.x;     // < 9830400
    int bt = idx / 80;
    int k4 = idx - bt * 80;
    int b = bt / 15;
    int t = bt - b * 15;
    float mval = mask[bt];
    float4 v;
    if (k4 < 64) {
        v = *(const float4*)(obs + (size_t)(b * NT + 7 + t) * OBS + k4 * 4);
    } else {
        v = *(const float4*)(act + (size_t)(b * NT + 7 + t) * ACTD + (k4 - 64) * 4);
    }
    v.x *= mval; v.y *= mval; v.z *= mval; v.w *= mval;
    ((float4*)out_pad)[idx] = v;
}

extern "C" void kernel_launch(void* const* d_in, const int* in_sizes, int n_in,
                              void* d_out, int out_size, void* d_ws, size_t ws_size,
                              hipStream_t stream) {
    const float* obs = (const float*)d_in[0];
    const float* act = (const float*)d_in[1];
    const float* Wih = (const float*)d_in[2];
    const float* Whh = (const float*)d_in[3];
    const float* bih = (const float*)d_in[4];
    const float* bhh = (const float*)d_in[5];
    const float* lng = (const float*)d_in[6];
    const float* lnb = (const float*)d_in[7];
    const float* W1  = (const float*)d_in[8];
    const float* b1  = (const float*)d_in[9];
    const float* W2  = (const float*)d_in[10];
    const float* b2  = (const float*)d_in[11];
    const float* W3  = (const float*)d_in[12];
    const float* b3  = (const float*)d_in[13];

    float* out      = (float*)d_out;
    float* out_wl   = out;                      // 8192
    float* out_pad  = out + NB;                 // 39,321,600
    float* out_mask = out + NB + NB * 15 * 320; // 122,880

    // Stage gi (122880*96 floats = 11.8M) inside the padded_window region;
    // it is consumed by k2 before k3 overwrites it.
    float* gi = out_pad;

    k1_gi<<<480, 256, 0, stream>>>(obs, act, Wih, bih, gi);
    k2_head<<<NB, 64, 0, stream>>>(obs, act, Whh, bhh, lng, lnb,
                                   W1, b1, W2, b2, W3, b3,
                                   gi, out_wl, out_mask);
    k3_window<<<38400, 256, 0, stream>>>(obs, act, out_mask, out_pad);
}

// Round 6
// 555.402 us; speedup vs baseline: 2.0786x; 1.1363x over previous
//
#include <hip/hip_runtime.h>
#include <math.h>

#define OBS 256
#define ACTD 64
#define NB 8192
#define NT 22
#define NSTEP 15

// ---------------------------------------------------------------------------
// Kernel 1: gi = x[122880 x 320] @ W_ih^T[320 x 96] + b_ih, tiled GEMM.
// R8 fix (THE fix): the epilogue's `#pragma unroll 1 for(p)` indexed
// acc[2*p+mm][j] with runtime p -> dynamic index -> compiler placed the
// ENTIRE acc[8][12] in scratch (rule #20). Every main-loop fmaf was a
// buffer_load+fma+buffer_store: that was the ~500 MB WRITE_SIZE and the
// 116-reg allocation of R5. Fully unrolling the 4-pass epilogue makes all
// acc indices compile-time -> acc lives in VGPRs (~200 live regs < 256).
//  - Block: 256 threads (4 waves) owns 256 rows x all 96 j. Grid 480 exact.
//  - K-chunked by 32. x staged global->reg->LDS, word-XOR swizzle
//    (compute-phase ds_read_b32 bank-conflict-free).
//  - Weights: global float2 loads (wave-uniform address, L1-hot), no LDS.
//  - Accumulation order per output: bias then k ascending, identical to
//    R0-R7 -> bit-exact (absmax 0.0).
// ---------------------------------------------------------------------------
__global__ __launch_bounds__(256, 1) void k1_gi(
    const float* __restrict__ obs, const float* __restrict__ act,
    const float* __restrict__ Wih, const float* __restrict__ bih,
    float* __restrict__ gi)
{
    __shared__ float lds[8192];   // 32KB: x chunk [256 rows][32 k] swizzled

    const int tid = threadIdx.x;
    const int blk = blockIdx.x;

    // staging mapping: thread loads 8 float4s, rows (tid>>3)+32q, f4 = tid&7
    const int f4o  = (tid & 7) * 4;
    const int srow = tid >> 3;            // 0..31
    int row_base[8];                       // (b*NT + t) per staged row
#pragma unroll
    for (int q = 0; q < 8; ++q) {
        int g = blk * 256 + srow + 32 * q;
        int b = g / 15;
        int t = g - b * 15;
        row_base[q] = b * NT + t;
    }

    // compute mapping
    const int jg = tid >> 5;              // 0..7  -> j tile [jg*12, jg*12+12)
    const int s  = tid & 31;              // row lane: rows s+32m
    const float* wbase = Wih + (size_t)(jg * 12) * 320;

    // prologue: load chunk 0 (kb=0, obs)
    float4 xs[8];
#pragma unroll
    for (int q = 0; q < 8; ++q)
        xs[q] = *(const float4*)(obs + (size_t)row_base[q] * OBS + f4o);

    float acc[8][12];
#pragma unroll
    for (int m = 0; m < 8; ++m)
#pragma unroll
        for (int j = 0; j < 12; ++j)
            acc[m][j] = bih[jg * 12 + j];

#pragma unroll 1
    for (int c = 0; c < 10; ++c) {
        const int kb = 32 * c;
        __syncthreads();                       // prev compute done with LDS
        // stage regs -> LDS with word-XOR swizzle
#pragma unroll
        for (int q = 0; q < 8; ++q) {
            int base = (srow + 32 * q) * 32;
            float v0 = xs[q].x, v1 = xs[q].y, v2 = xs[q].z, v3 = xs[q].w;
            lds[base + ((f4o + 0) ^ srow)] = v0;
            lds[base + ((f4o + 1) ^ srow)] = v1;
            lds[base + ((f4o + 2) ^ srow)] = v2;
            lds[base + ((f4o + 3) ^ srow)] = v3;
        }
        // issue next chunk's loads (latency hides under compute below)
        if (c < 9) {
            int kb2 = kb + 32;
#pragma unroll
            for (int q = 0; q < 8; ++q) {
                const float* src = (kb2 < 256)
                    ? (obs + (size_t)row_base[q] * OBS + kb2 + f4o)
                    : (act + (size_t)row_base[q] * ACTD + (kb2 - 256) + f4o);
                xs[q] = *(const float4*)src;
            }
        }
        __syncthreads();                       // LDS chunk ready
        // compute 32 k values in 2-k steps
#pragma unroll 1
        for (int st = 0; st < 16; ++st) {
            const int k0 = 2 * st;
            float wv[12][2];
#pragma unroll
            for (int j = 0; j < 12; ++j) {
                float2 w2 = *(const float2*)(wbase + (size_t)j * 320 + kb + k0);
                wv[j][0] = w2.x; wv[j][1] = w2.y;
            }
            float xv[8][2];
#pragma unroll
            for (int m = 0; m < 8; ++m) {
                xv[m][0] = lds[(s + 32 * m) * 32 + ((k0 + 0) ^ s)];
                xv[m][1] = lds[(s + 32 * m) * 32 + ((k0 + 1) ^ s)];
            }
#pragma unroll
            for (int m = 0; m < 8; ++m)
#pragma unroll
                for (int j = 0; j < 12; ++j) {
                    acc[m][j] = fmaf(wv[j][0], xv[m][0], acc[m][j]);
                    acc[m][j] = fmaf(wv[j][1], xv[m][1], acc[m][j]);
                }
        }
    }

    // epilogue: 4 transpose passes through LDS (64 rows x 96, stride 97)
    // FULLY UNROLLED: p must be compile-time so acc[] indices are static
    // (runtime p put acc in scratch -- rule #20 -- R3..R5's spill bug).
#pragma unroll
    for (int p = 0; p < 4; ++p) {
        __syncthreads();
#pragma unroll
        for (int mm = 0; mm < 2; ++mm) {
            const int m = 2 * p + mm;          // compile-time constant now
            int lr = s + 32 * mm;              // local row 0..63
#pragma unroll
            for (int j = 0; j < 12; ++j)
                lds[lr * 97 + jg * 12 + j] = acc[m][j];
        }
        __syncthreads();
#pragma unroll
        for (int q = 0; q < 6; ++q) {
            int s4 = tid + 256 * q;            // 0..1535
            int r  = s4 / 24;
            int c4 = s4 - r * 24;
            float4 v = make_float4(lds[r * 97 + 4 * c4 + 0],
                                   lds[r * 97 + 4 * c4 + 1],
                                   lds[r * 97 + 4 * c4 + 2],
                                   lds[r * 97 + 4 * c4 + 3]);
            *(float4*)(gi + (size_t)blk * 24576 + p * 6144 + 4 * s4) = v;
        }
    }
}

// ---------------------------------------------------------------------------
// Kernel 2: per-row GRU recurrence + features + layernorm + MLP + argmax.
// One wave (64 threads) per batch row. Lanes mirror mod 32 for the gates.
// ---------------------------------------------------------------------------
__global__ __launch_bounds__(64, 2) void k2_head(
    const float* __restrict__ obs, const float* __restrict__ act,
    const float* __restrict__ Whh, const float* __restrict__ bhh,
    const float* __restrict__ lng, const float* __restrict__ lnb,
    const float* __restrict__ W1, const float* __restrict__ b1,
    const float* __restrict__ W2, const float* __restrict__ b2,
    const float* __restrict__ W3, const float* __restrict__ b3,
    const float* __restrict__ gi,
    float* __restrict__ out_wl, float* __restrict__ out_mask)
{
    int b = blockIdx.x;
    int l = threadIdx.x;        // 0..63
    int jj = l & 31;            // gate row index (lanes 32..63 mirror 0..31)

    float wr[32], wz[32], wn[32];
#pragma unroll
    for (int k = 0; k < 32; ++k) {
        wr[k] = Whh[(0  + jj) * 32 + k];
        wz[k] = Whh[(32 + jj) * 32 + k];
        wn[k] = Whh[(64 + jj) * 32 + k];
    }
    float br = bhh[jj], bz = bhh[32 + jj], bn = bhh[64 + jj];

    float hfull[32];
#pragma unroll
    for (int k = 0; k < 32; ++k) hfull[k] = 0.0f;
    float hown = 0.0f;

    const float* gib = gi + (size_t)b * NSTEP * 96;
    for (int t = 0; t < NSTEP; ++t) {
        float gi_r = gib[t * 96 + jj];
        float gi_z = gib[t * 96 + 32 + jj];
        float gi_n = gib[t * 96 + 64 + jj];
        float ar = br, az = bz, an = bn;
#pragma unroll
        for (int k = 0; k < 32; ++k) {
            ar = fmaf(wr[k], hfull[k], ar);
            az = fmaf(wz[k], hfull[k], az);
            an = fmaf(wn[k], hfull[k], an);
        }
        float r = 1.0f / (1.0f + expf(-(gi_r + ar)));
        float z = 1.0f / (1.0f + expf(-(gi_z + az)));
        float n = tanhf(gi_n + r * an);
        hown = (1.0f - z) * n + z * hown;
#pragma unroll
        for (int k = 0; k < 32; ++k) hfull[k] = __shfl(hown, k, 64);
    }

    // ---- features ----
    float o14v[4], o13v[4], o12v[4], o11v[4];
#pragma unroll
    for (int q = 0; q < 4; ++q) {
        int i = l + 64 * q;
        o14v[q] = obs[(size_t)(b * NT + 14) * OBS + i];
        o13v[q] = obs[(size_t)(b * NT + 13) * OBS + i];
        o12v[q] = obs[(size_t)(b * NT + 12) * OBS + i];
        o11v[q] = obs[(size_t)(b * NT + 11) * OBS + i];
    }
    float ap = act[(size_t)(b * NT + 13) * ACTD + l];

    float m = fmaxf(fmaxf(o14v[0], o14v[1]), fmaxf(o14v[2], o14v[3]));
#pragma unroll
    for (int o = 32; o >= 1; o >>= 1) m = fmaxf(m, __shfl_xor(m, o, 64));
    float e[4];
    float S = 0.0f, so = 0.0f;
#pragma unroll
    for (int q = 0; q < 4; ++q) {
        e[q] = expf(o14v[q] - m);
        S += e[q];
        so += o14v[q];
    }
#pragma unroll
    for (int o = 32; o >= 1; o >>= 1) { S += __shfl_xor(S, o, 64); so += __shfl_xor(so, o, 64); }
    float ent = 0.0f;
#pragma unroll
    for (int q = 0; q < 4; ++q) {
        float p = e[q] / S;
        ent += p * logf(p + 1e-8f);
    }
#pragma unroll
    for (int o = 32; o >= 1; o >>= 1) ent += __shfl_xor(ent, o, 64);
    ent = -ent;

    float d1 = 0.0f, d2 = 0.0f, d3 = 0.0f;
#pragma unroll
    for (int q = 0; q < 4; ++q) {
        float a = o12v[q] - o11v[q]; d1 = fmaf(a, a, d1);
        a = o13v[q] - o12v[q];       d2 = fmaf(a, a, d2);
        a = o14v[q] - o13v[q];       d3 = fmaf(a, a, d3);
    }
#pragma unroll
    for (int o = 32; o >= 1; o >>= 1) {
        d1 += __shfl_xor(d1, o, 64); d2 += __shfl_xor(d2, o, 64); d3 += __shfl_xor(d3, o, 64);
    }
    float roc = (sqrtf(d1) + sqrtf(d2) + sqrtf(d3)) / 3.0f;

    float sa = ap;
#pragma unroll
    for (int o = 32; o >= 1; o >>= 1) sa += __shfl_xor(sa, o, 64);
    float mu_o = so / 256.0f;
    float mu_a = sa / 256.0f;
    float s_oa = 0.0f, s_oo = 0.0f, s_aa = 0.0f;
#pragma unroll
    for (int q = 0; q < 4; ++q) {
        float ov = o14v[q] - mu_o;
        float av = ((q == 0) ? ap : 0.0f) - mu_a;
        s_oa = fmaf(ov, av, s_oa);
        s_oo = fmaf(ov, ov, s_oo);
        s_aa = fmaf(av, av, s_aa);
    }
#pragma unroll
    for (int o = 32; o >= 1; o >>= 1) {
        s_oa += __shfl_xor(s_oa, o, 64); s_oo += __shfl_xor(s_oo, o, 64); s_aa += __shfl_xor(s_aa, o, 64);
    }
    float corr = s_oa / (sqrtf(s_oo) * sqrtf(s_aa) + 1e-8f);

    float fsum = ent + roc + corr;
#pragma unroll
    for (int k = 0; k < 32; ++k) fsum += hfull[k];
    float mu = fsum / 35.0f;
    float vs = (ent - mu) * (ent - mu) + (roc - mu) * (roc - mu) + (corr - mu) * (corr - mu);
#pragma unroll
    for (int k = 0; k < 32; ++k) { float dd = hfull[k] - mu; vs = fmaf(dd, dd, vs); }
    float inv_sv = 1.0f / sqrtf(vs / 35.0f + 1e-5f);

    float x1 = b1[l];
#pragma unroll
    for (int k = 0; k < 35; ++k) {
        float f = (k == 0) ? ent : (k == 1) ? roc : (k == 2) ? corr : hfull[k - 3];
        float fnk = (f - mu) * inv_sv * lng[k] + lnb[k];
        x1 = fmaf(W1[l * 35 + k], fnk, x1);
    }
    x1 = fmaxf(x1, 0.0f);

    float x2 = b2[jj];
#pragma unroll
    for (int k = 0; k < 64; ++k)
        x2 = fmaf(W2[jj * 64 + k], __shfl(x1, k, 64), x2);
    x2 = fmaxf(x2, 0.0f);

    int lr = (l < 14) ? l : 0;
    float lg = b3[lr];
#pragma unroll
    for (int k = 0; k < 32; ++k)
        lg = fmaf(W3[lr * 32 + k], __shfl(x2, k, 64), lg);

    float best = -3.402823466e38f;
    int bi = 0;
#pragma unroll
    for (int j = 0; j < 14; ++j) {
        float v = __shfl(lg, j, 64);
        if (v > best) { best = v; bi = j; }
    }
    int wl = bi + 2;
    if (l == 0) out_wl[b] = (float)wl;
    int ss = (wl - 1) >> 1;
    int ee = wl >> 1;
    if (l < 15) {
        int off = l - 7;
        out_mask[b * 15 + l] = (off >= -ss && off <= ee) ? 1.0f : 0.0f;
    }
}

// ---------------------------------------------------------------------------
// Kernel 3: padded_window = concat(obs[:,7:22], act[:,7:22]) * mask
// ---------------------------------------------------------------------------
__global__ __launch_bounds__(256) void k3_window(
    const float* __restrict__ obs, const float* __restrict__ act,
    const float* __restrict__ mask, float* __restrict__ out_pad)
{
    int idx = blockIdx.x * 256 + threadIdx.x;     // < 9830400
    int bt = idx / 80;
    int k4 = idx - bt * 80;
    int b = bt / 15;
    int t = bt - b * 15;
    float mval = mask[bt];
    float4 v;
    if (k4 < 64) {
        v = *(const float4*)(obs + (size_t)(b * NT + 7 + t) * OBS + k4 * 4);
    } else {
        v = *(const float4*)(act + (size_t)(b * NT + 7 + t) * ACTD + (k4 - 64) * 4);
    }
    v.x *= mval; v.y *= mval; v.z *= mval; v.w *= mval;
    ((float4*)out_pad)[idx] = v;
}

extern "C" void kernel_launch(void* const* d_in, const int* in_sizes, int n_in,
                              void* d_out, int out_size, void* d_ws, size_t ws_size,
                              hipStream_t stream) {
    const float* obs = (const float*)d_in[0];
    const float* act = (const float*)d_in[1];
    const float* Wih = (const float*)d_in[2];
    const float* Whh = (const float*)d_in[3];
    const float* bih = (const float*)d_in[4];
    const float* bhh = (const float*)d_in[5];
    const float* lng = (const float*)d_in[6];
    const float* lnb = (const float*)d_in[7];
    const float* W1  = (const float*)d_in[8];
    const float* b1  = (const float*)d_in[9];
    const float* W2  = (const float*)d_in[10];
    const float* b2  = (const float*)d_in[11];
    const float* W3  = (const float*)d_in[12];
    const float* b3  = (const float*)d_in[13];

    float* out      = (float*)d_out;
    float* out_wl   = out;                      // 8192
    float* out_pad  = out + NB;                 // 39,321,600
    float* out_mask = out + NB + NB * 15 * 320; // 122,880

    // Stage gi (122880*96 floats = 11.8M) inside the padded_window region;
    // it is consumed by k2 before k3 overwrites it.
    float* gi = out_pad;

    k1_gi<<<480, 256, 0, stream>>>(obs, act, Wih, bih, gi);
    k2_head<<<NB, 64, 0, stream>>>(obs, act, Whh, bhh, lng, lnb,
                                   W1, b1, W2, b2, W3, b3,
                                   gi, out_wl, out_mask);
    k3_window<<<38400, 256, 0, stream>>>(obs, act, out_mask, out_pad);
}